// Round 10
// baseline (166.350 us; speedup 1.0000x reference)
//
#include <hip/hip_runtime.h>
#include <hip/hip_bf16.h>
#include <stdint.h>
#include <math.h>

#define KDIM 2304   // 9 * 256
#define PSF  2576   // k_fused plane stride (shorts): 64*40 + 16 (8-bank shift)
#define PSO  1296   // k_offs plane stride (shorts): 32*40 + 16

typedef __attribute__((ext_vector_type(8))) short bf16x8;
typedef __attribute__((ext_vector_type(8))) unsigned short u16x8;
typedef __attribute__((ext_vector_type(4))) float f32x4;

__device__ inline unsigned short f2bf(float f) {
  union { float f; unsigned int u; } v; v.f = f;
  unsigned int u = v.u;
  unsigned int r = (u + 0x7FFFu + ((u >> 16) & 1u)) >> 16;
  return (unsigned short)r;
}
__device__ inline float bf2f(unsigned short h) {
  union { unsigned int u; float f; } v; v.u = ((unsigned int)h) << 16;
  return v.f;
}

// ---------------------------------------------------------------------------
// Kernel 1: x (B,C,H,W) fp32 -> xTb (B,H,W,C) bf16
// ---------------------------------------------------------------------------
__global__ __launch_bounds__(256) void k_transpose(const float* __restrict__ x,
                                                   unsigned short* __restrict__ xTb) {
  __shared__ float tile[32][33];
  int t = threadIdx.x;
  int tx = t & 31, ty = t >> 5;
  int p0 = blockIdx.x * 32;
  int c0 = blockIdx.y * 32;
  int b  = blockIdx.z;
  const float* xb = x + ((size_t)b << 20);
#pragma unroll
  for (int i = 0; i < 4; ++i) {
    int c = c0 + ty + i * 8;
    tile[ty + i * 8][tx] = xb[((size_t)c << 12) + p0 + tx];
  }
  __syncthreads();
  unsigned short* ob = xTb + ((size_t)b << 20);
#pragma unroll
  for (int i = 0; i < 4; ++i) {
    int p = p0 + ty + i * 8;
    ob[(((size_t)p) << 8) + c0 + tx] = f2bf(tile[tx][ty + i * 8]);
  }
}

// ---------------------------------------------------------------------------
// Kernel 2: weight prep (Wpk in A-fragment order; Wob row-major; zero page).
// ---------------------------------------------------------------------------
__global__ __launch_bounds__(256) void k_wprep(const float* __restrict__ dcn_w,
                                               const float* __restrict__ offset_w,
                                               unsigned short* __restrict__ Wpk,
                                               unsigned short* __restrict__ Wob,
                                               unsigned short* __restrict__ zp) {
  int gid = blockIdx.x * 256 + threadIdx.x;
  const int N1 = 72 * 8192;
  const int N2 = 32 * KDIM;
  if (gid < N1) {
    int j = gid & 7;
    int lane = (gid >> 3) & 63;
    int mb = (gid >> 9) & 15;
    int kc = gid >> 13;
    int row = mb * 16 + (lane & 15);
    int gk = kc * 32 + ((lane >> 4) << 3) + j;
    int c = gk & 255, kidx = gk >> 8;
    Wpk[gid] = f2bf(dcn_w[((size_t)(row * 256 + c)) * 9 + kidx]);
  } else if (gid < N1 + N2) {
    int g = gid - N1;
    int ch = g / KDIM, k = g % KDIM;
    int kidx = k >> 8, c = k & 255;
    Wob[g] = (ch < 27) ? f2bf(offset_w[((size_t)(ch * 256 + c)) * 9 + kidx])
                       : (unsigned short)0;
  } else if (gid < N1 + N2 + 512) {
    zp[gid - N1 - N2] = 0;
  }
}

// ---------------------------------------------------------------------------
// Kernel 3: offset conv GEMM, phase-structured, coalesced staging.
//  BM=32 x 32ch, grid 512 (2 blocks/CU), 256 thr / 4 waves (16m x 16n each).
//  Staging roles: row = (t>>5) + 8i, slice = t&31 -> wave gathers are 2x512B
//  contiguous segments. Issue(p+1) before barrier so drains are cheap.
// ---------------------------------------------------------------------------
__global__ __launch_bounds__(256, 2) void k_offs_gemm(const unsigned short* __restrict__ xTb,
                                                      const unsigned short* __restrict__ Wob,
                                                      const unsigned short* __restrict__ zp,
                                                      float* __restrict__ O2) {
  __shared__ __align__(16) unsigned short As[8 * PSO];   // 20.7 KB
  int t = threadIdx.x;
  int wv = t >> 6, lane = t & 63;
  int cl = lane & 15, q = lane >> 4;
  int wm = wv & 1, wn = wv >> 1;
  int n0 = blockIdx.x * 32;

  int rowb = t >> 5;           // 0..7
  int s = t & 31;
  int kcp = s >> 2, soff = (s & 3) * 8, sE = s * 8;

  int hh[4], ww[4];
  const unsigned short* xbb[4];
#pragma unroll
  for (int i = 0; i < 4; ++i) {
    int row = n0 + rowb + 8 * i;
    int b_ = row >> 12, hw = row & 4095;
    hh[i] = hw >> 6; ww[i] = hw & 63;
    xbb[i] = xTb + ((size_t)b_ << 20);
  }

  auto gsrc = [&](int p, int i) -> const unsigned short* {
    int di = p / 3 - 1, dj = p % 3 - 1;
    int y = hh[i] + di, xx = ww[i] + dj;
    bool v = ((unsigned)y < 64u) && ((unsigned)xx < 64u);
    return v ? xbb[i] + (((size_t)((y << 6) + xx)) << 8) + sE : zp + sE;
  };

  f32x4 acc = {};
  u16x8 g[4];
#pragma unroll
  for (int i = 0; i < 4; ++i) g[i] = *(const u16x8*)gsrc(0, i);

#pragma unroll 1
  for (int p = 0; p < 9; ++p) {
    // commit(p)
#pragma unroll
    for (int i = 0; i < 4; ++i)
      *(u16x8*)(&As[kcp * PSO + (rowb + 8 * i) * 40 + soff]) = g[i];
    // issue(p+1)
    if (p < 8) {
#pragma unroll
      for (int i = 0; i < 4; ++i) g[i] = *(const u16x8*)gsrc(p + 1, i);
    }
    __syncthreads();
    // mmphase(p)
#pragma unroll
    for (int k2 = 0; k2 < 8; ++k2) {
      int kt = p * 8 + k2;
      bf16x8 aF = *(const bf16x8*)(&As[k2 * PSO + (wm * 16 + cl) * 40 + q * 8]);
      bf16x8 bF = *(const bf16x8*)(Wob + (size_t)(wn * 16 + cl) * KDIM + kt * 32 + q * 8);
      acc = __builtin_amdgcn_mfma_f32_16x16x32_bf16(aF, bF, acc, 0, 0, 0);
    }
    __syncthreads();
  }

#pragma unroll
  for (int r = 0; r < 4; ++r)
    O2[(size_t)(n0 + wm * 16 + q * 4 + r) * 32 + wn * 16 + cl] = acc[r];
}

// ---------------------------------------------------------------------------
// Kernel 4: sampling weights/offsets table (bias folded here).
// ---------------------------------------------------------------------------
__global__ __launch_bounds__(256) void k_sweights(const float* __restrict__ O2,
                                                  const float* __restrict__ offb,
                                                  float* __restrict__ SW) {
  int gid = blockIdx.x * 256 + threadIdx.x;
  if (gid >= 9 * 16384) return;
  int k = gid >> 14;
  int bhw = gid & 16383;
  int h = (bhw >> 6) & 63, w = bhw & 63;

  const float* o = O2 + (size_t)bhw * 32;
  float dy = o[2 * k]     + offb[2 * k];
  float dx = o[2 * k + 1] + offb[2 * k + 1];
  float mv = o[18 + k]    + offb[18 + k];
  float mask = 1.0f / (1.0f + expf(-mv));

  float py = (float)(h - 1 + k / 3) + dy;
  float px = (float)(w - 1 + k % 3) + dx;
  float y0f = floorf(py), x0f = floorf(px);
  float wy = py - y0f, wx = px - x0f;
  int y0 = (int)y0f, x0 = (int)x0f;
  int y1 = y0 + 1, x1 = x0 + 1;

  float vy0 = (y0 >= 0 && y0 < 64) ? 1.f : 0.f;
  float vy1 = (y1 >= 0 && y1 < 64) ? 1.f : 0.f;
  float vx0 = (x0 >= 0 && x0 < 64) ? 1.f : 0.f;
  float vx1 = (x1 >= 0 && x1 < 64) ? 1.f : 0.f;
  int y0c = min(max(y0, 0), 63), y1c = min(max(y1, 0), 63);
  int x0c = min(max(x0, 0), 63), x1c = min(max(x1, 0), 63);

  float4 wv4;
  wv4.x = (1.f - wy) * (1.f - wx) * vy0 * vx0 * mask;
  wv4.y = (1.f - wy) * wx * vy0 * vx1 * mask;
  wv4.z = wy * (1.f - wx) * vy1 * vx0 * mask;
  wv4.w = wy * wx * vy1 * vx1 * mask;
  uint4 ov;
  ov.x = (unsigned)(((y0c << 6) + x0c) << 8);
  ov.y = (unsigned)(((y0c << 6) + x1c) << 8);
  ov.z = (unsigned)(((y1c << 6) + x0c) << 8);
  ov.w = (unsigned)(((y1c << 6) + x1c) << 8);

  float* p = SW + (size_t)gid * 8;
  *(float4*)p = wv4;
  *(uint4*)(p + 4) = ov;
}

// ---------------------------------------------------------------------------
// Kernel 5: fused sample + main GEMM.
//  BM=256 (full M) x BN=64, grid 256, 512 thr / 8 waves (4m x 2n; 64x32 each).
//  Phase (kidx) structure: sample 64-row x 256-ch panel into single-buffer
//  kc-plane LDS; gathers for p+1 issued BEFORE blend(p) (registers), so the
//  barrier's vmcnt drain finds them retired. Coalesced roles: wave gather =
//  2 x 512B contiguous segments. A-fragments direct from packed Wpk,
//  prefetched one k2 ahead. 2 barriers/phase (18 total).
// ---------------------------------------------------------------------------
__global__ __launch_bounds__(512, 2) void k_fused(const unsigned short* __restrict__ Wpk,
                                                  const unsigned short* __restrict__ xTb,
                                                  const float* __restrict__ SW,
                                                  float* __restrict__ out) {
  __shared__ __align__(16) unsigned short Bs[8 * PSF];   // 41.2 KB
  int t = threadIdx.x;
  int wv = t >> 6, lane = t & 63;
  int wm = wv & 3, wn = wv >> 2;
  int cl = lane & 15, q = lane >> 4;
  int n0 = blockIdx.x * 64;
  int b  = n0 >> 12;
  const unsigned short* xb = xTb + ((size_t)b << 20);

  int rowb = t >> 5;            // 0..15
  int s = t & 31;
  int kcp = s >> 2, soff = (s & 3) * 8, sE = s * 8;

  f32x4 acc[4][2] = {};
  float4 wqs[4], wqc[4];
  uint4  ovc[4];
  u16x8 g0[4], g1[4], g2[4], g3[4];
  bf16x8 aC[4], aN[4];

  // prologue: SW(0) -> gathers(0); prefetch SW(1); preload aC(phase0,k2=0)
#pragma unroll
  for (int i = 0; i < 4; ++i) {
    const float* sw = SW + ((size_t)(n0 + rowb + 16 * i)) * 8;
    wqc[i] = *(const float4*)sw; ovc[i] = *(const uint4*)(sw + 4);
  }
#pragma unroll
  for (int i = 0; i < 4; ++i) {
    g0[i] = *(const u16x8*)(xb + ovc[i].x + sE);
    g1[i] = *(const u16x8*)(xb + ovc[i].y + sE);
    g2[i] = *(const u16x8*)(xb + ovc[i].z + sE);
    g3[i] = *(const u16x8*)(xb + ovc[i].w + sE);
    wqs[i] = wqc[i];
  }
#pragma unroll
  for (int i = 0; i < 4; ++i) {
    const float* sw = SW + ((size_t)((1 << 14) + n0 + rowb + 16 * i)) * 8;
    wqc[i] = *(const float4*)sw; ovc[i] = *(const uint4*)(sw + 4);
  }
#pragma unroll
  for (int i = 0; i < 4; ++i)
    aC[i] = *(const bf16x8*)(Wpk + ((size_t)((wm * 4 + i) * 64 + lane)) * 8);

#pragma unroll 1
  for (int p = 0; p < 9; ++p) {
    // commit(p): blend held gathers -> Bs
#pragma unroll
    for (int i = 0; i < 4; ++i) {
      float sv[8];
#pragma unroll
      for (int c = 0; c < 8; ++c)
        sv[c] = wqs[i].x * bf2f(g0[i][c]) + wqs[i].y * bf2f(g1[i][c])
              + wqs[i].z * bf2f(g2[i][c]) + wqs[i].w * bf2f(g3[i][c]);
      union { __hip_bfloat162 h2[4]; u16x8 v; } pk;
#pragma unroll
      for (int c = 0; c < 4; ++c)
        pk.h2[c] = __float22bfloat162_rn(make_float2(sv[2 * c], sv[2 * c + 1]));
      *(u16x8*)(&Bs[kcp * PSF + (rowb + 16 * i) * 40 + soff]) = pk.v;
    }
    // issue(p+1): gathers into registers (land during barrier+mmphase)
    if (p < 8) {
#pragma unroll
      for (int i = 0; i < 4; ++i) {
        g0[i] = *(const u16x8*)(xb + ovc[i].x + sE);
        g1[i] = *(const u16x8*)(xb + ovc[i].y + sE);
        g2[i] = *(const u16x8*)(xb + ovc[i].z + sE);
        g3[i] = *(const u16x8*)(xb + ovc[i].w + sE);
        wqs[i] = wqc[i];
      }
    }
    __syncthreads();
    // SW(p+2) prefetch (drains at next barrier with full mmphase cover)
    if (p < 7) {
#pragma unroll
      for (int i = 0; i < 4; ++i) {
        const float* sw = SW + ((size_t)(((p + 2) << 14) + n0 + rowb + 16 * i)) * 8;
        wqc[i] = *(const float4*)sw; ovc[i] = *(const uint4*)(sw + 4);
      }
    }
    // mmphase(p)
#pragma unroll
    for (int k2 = 0; k2 < 8; ++k2) {
      int kt = p * 8 + k2;
      int ktn = (kt + 1 < 72) ? kt + 1 : kt;
#pragma unroll
      for (int i = 0; i < 4; ++i)
        aN[i] = *(const bf16x8*)(Wpk + ((size_t)((ktn * 16 + wm * 4 + i) * 64 + lane)) * 8);
      bf16x8 bF[2];
#pragma unroll
      for (int j = 0; j < 2; ++j)
        bF[j] = *(const bf16x8*)(&Bs[k2 * PSF + (wn * 32 + j * 16 + cl) * 40 + q * 8]);
#pragma unroll
      for (int i = 0; i < 4; ++i) {
        acc[i][0] = __builtin_amdgcn_mfma_f32_16x16x32_bf16(aC[i], bF[0], acc[i][0], 0, 0, 0);
        acc[i][1] = __builtin_amdgcn_mfma_f32_16x16x32_bf16(aC[i], bF[1], acc[i][1], 0, 0, 0);
      }
#pragma unroll
      for (int i = 0; i < 4; ++i) aC[i] = aN[i];
    }
    __syncthreads();
  }

  // epilogue: C/D layout col=lane&15, row=quad*4+reg
  float* ob = out + (((size_t)b) << 20);
  int hwb = n0 & 4095;
#pragma unroll
  for (int i = 0; i < 4; ++i) {
    int mbase = wm * 64 + i * 16 + q * 4;
#pragma unroll
    for (int j = 0; j < 2; ++j) {
      float* op = ob + hwb + wn * 32 + j * 16 + cl;
#pragma unroll
      for (int rr = 0; rr < 4; ++rr)
        op[((size_t)(mbase + rr)) << 12] = acc[i][j][rr];
    }
  }
}

// ---------------------------------------------------------------------------
extern "C" void kernel_launch(void* const* d_in, const int* in_sizes, int n_in,
                              void* d_out, int out_size, void* d_ws, size_t ws_size,
                              hipStream_t stream) {
  const float* x        = (const float*)d_in[0];
  const float* offset_w = (const float*)d_in[1];
  const float* offset_b = (const float*)d_in[2];
  const float* dcn_w    = (const float*)d_in[3];
  float* out = (float*)d_out;

  char* ws = (char*)d_ws;
  size_t off = 0;
  auto carve = [&](size_t bytes) -> void* {
    void* p = ws + off;
    off += (bytes + 255) & ~(size_t)255;
    return p;
  };
  unsigned short* xTb = (unsigned short*)carve(4ull * 64 * 64 * 256 * 2);   // 8 MB
  unsigned short* Wpk = (unsigned short*)carve(72ull * 8192 * 2);           // 1.125 MB
  unsigned short* Wob = (unsigned short*)carve(32ull * KDIM * 2);           // 144 KB
  unsigned short* zp  = (unsigned short*)carve(1024);                       // zero page
  float*          O2  = (float*)carve(16384ull * 32 * 4);                   // 2 MB
  float*          SW  = (float*)carve(9ull * 16384 * 8 * 4);                // 4.5 MB
  (void)ws_size; (void)in_sizes; (void)n_in; (void)out_size;

  k_transpose<<<dim3(128, 8, 4), 256, 0, stream>>>(x, xTb);
  k_wprep<<<dim3((72 * 8192 + 32 * KDIM + 512 + 255) / 256), 256, 0, stream>>>(
      dcn_w, offset_w, Wpk, Wob, zp);
  k_offs_gemm<<<dim3(512), 256, 0, stream>>>(xTb, Wob, zp, O2);
  k_sweights<<<dim3((9 * 16384 + 255) / 256), 256, 0, stream>>>(O2, offset_b, SW);
  k_fused<<<dim3(256), 512, 0, stream>>>(Wpk, xTb, SW, out);
}